// Round 1
// baseline (2256.747 us; speedup 1.0000x reference)
//
#include <hip/hip_runtime.h>
#include <cstdint>
#include <cstddef>

using bf16 = __bf16;
typedef __bf16 bf16x8 __attribute__((ext_vector_type(8)));
typedef __bf16 bf16x4 __attribute__((ext_vector_type(4)));
typedef float  f32x4  __attribute__((ext_vector_type(4)));

// ---- problem constants ----
constexpr int NB   = 2;      // batch
constexpr int NN   = 2048;   // seq
constexpr int DIM  = 1024;
constexpr int NH   = 8;
constexpr int DH   = 64;
constexpr int INNER= 512;
constexpr int FF   = 2730;
constexpr int FFP  = 2816;   // padded FF (22*128)
constexpr int MROW = NB * NN;   // 4096
constexpr int NLAY = 6;

// ======================= bias table ==========================
__global__ void btab_kernel(const float* __restrict__ rel, float* __restrict__ btab) {
  int d = blockIdx.x * 256 + threadIdx.x;
  if (d >= NN) return;
  int bucket;
  if (d < 16) bucket = d;
  else {
    int vl = 16 + (int)(logf((float)d / 16.0f) / logf(8.0f) * 16.0f);
    bucket = vl < 31 ? vl : 31;
  }
  for (int h = 0; h < NH; ++h) btab[h * NN + d] = rel[bucket * NH + h];
}

// ============== weight convert + transpose (+pad, +scale) ==============
// T[i][j] = (i<C && j<R) ? src[j][colOff+i]*scale : 0   (per layer z)
__global__ void conv_tr(const float* __restrict__ src, size_t srcLayer, int srcStride,
                        int colOff, int R, int C,
                        bf16* __restrict__ dst, size_t dstLayer, int Tcols, float scale) {
  __shared__ float tile[32][33];
  const int i0 = blockIdx.x * 32, j0 = blockIdx.y * 32, z = blockIdx.z;
  const float* s = src + (size_t)z * srcLayer;
  bf16* d = dst + (size_t)z * dstLayer;
  const int tx = threadIdx.x, ty = threadIdx.y;
#pragma unroll
  for (int k = 0; k < 4; ++k) {
    int j = j0 + ty + k * 8;
    int i = i0 + tx;
    float v = 0.0f;
    if (j < R && i < C) v = s[(size_t)j * srcStride + colOff + i] * scale;
    tile[ty + k * 8][tx] = v;
  }
  __syncthreads();
#pragma unroll
  for (int k = 0; k < 4; ++k) {
    int i = i0 + ty + k * 8;   // dst row
    int j = j0 + tx;           // dst col
    d[(size_t)i * Tcols + j] = (bf16)tile[tx][ty + k * 8];
  }
}

// ======================= LayerNorm ==========================
template <typename OUT>
__global__ void ln_kernel(const float* __restrict__ X, const float* __restrict__ G,
                          const float* __restrict__ Bt, OUT* __restrict__ out) {
  __shared__ float red[8];
  const int row = blockIdx.x, t = threadIdx.x;
  const float* xr = X + (size_t)row * DIM;
  float4 v = *(const float4*)(xr + t * 4);
  float s  = v.x + v.y + v.z + v.w;
  float s2 = v.x * v.x + v.y * v.y + v.z * v.z + v.w * v.w;
#pragma unroll
  for (int o = 1; o < 64; o <<= 1) { s += __shfl_xor(s, o); s2 += __shfl_xor(s2, o); }
  if ((t & 63) == 0) { red[t >> 6] = s; red[4 + (t >> 6)] = s2; }
  __syncthreads();
  float S  = red[0] + red[1] + red[2] + red[3];
  float S2 = red[4] + red[5] + red[6] + red[7];
  const float inv = 1.0f / (float)DIM;
  float mu = S * inv;
  float var = S2 * inv - mu * mu;
  float rstd = rsqrtf(var + 1e-5f);
  float4 g  = *(const float4*)(G + t * 4);
  float4 bb = *(const float4*)(Bt + t * 4);
  OUT* orow = out + (size_t)row * DIM + t * 4;
  orow[0] = (OUT)((v.x - mu) * rstd * g.x + bb.x);
  orow[1] = (OUT)((v.y - mu) * rstd * g.y + bb.y);
  orow[2] = (OUT)((v.z - mu) * rstd * g.z + bb.z);
  orow[3] = (OUT)((v.w - mu) * rstd * g.w + bb.w);
}

// ======================= GEMM: C[M,N] = A[M,K] @ B^T[N,K] ==========================
// 128x128 tile, BK=64, 4 waves (2x2), each wave 64x64 via 4x4 of 16x16x32 MFMA.
// MODE 0: store bf16 C.  MODE 1: Xr[idx] += acc (fp32 residual).
template <int MODE>
__launch_bounds__(256)
__global__ void gemm_bt(const bf16* __restrict__ A, const bf16* __restrict__ B,
                        int K, int N, bf16* __restrict__ Cb, float* __restrict__ Xr) {
  __shared__ bf16 As[128][64];
  __shared__ bf16 Bs[128][64];
  const int tid = threadIdx.x;
  const int lane = tid & 63, wave = tid >> 6;
  const int m0 = blockIdx.y * 128, n0 = blockIdx.x * 128;
  const int wm = (wave >> 1) * 64, wn = (wave & 1) * 64;
  f32x4 acc[4][4] = {};
  const int srow = tid >> 3;          // 0..31
  const int sgrp = (tid & 7) * 8;     // element col group
  const int fr = lane & 15, fg8 = (lane >> 4) * 8;

  bf16x8 ra[4], rb[4];
#pragma unroll
  for (int i = 0; i < 4; ++i) {
    ra[i] = *(const bf16x8*)&A[(size_t)(m0 + srow + i * 32) * K + sgrp];
    rb[i] = *(const bf16x8*)&B[(size_t)(n0 + srow + i * 32) * K + sgrp];
  }
  for (int kt = 0; kt < K; kt += 64) {
    __syncthreads();
#pragma unroll
    for (int i = 0; i < 4; ++i) {
      *(bf16x8*)&As[srow + i * 32][sgrp] = ra[i];
      *(bf16x8*)&Bs[srow + i * 32][sgrp] = rb[i];
    }
    __syncthreads();
    if (kt + 64 < K) {
#pragma unroll
      for (int i = 0; i < 4; ++i) {
        ra[i] = *(const bf16x8*)&A[(size_t)(m0 + srow + i * 32) * K + kt + 64 + sgrp];
        rb[i] = *(const bf16x8*)&B[(size_t)(n0 + srow + i * 32) * K + kt + 64 + sgrp];
      }
    }
#pragma unroll
    for (int kk = 0; kk < 64; kk += 32) {
      bf16x8 af[4], bfr[4];
#pragma unroll
      for (int m = 0; m < 4; ++m) af[m]  = *(const bf16x8*)&As[wm + m * 16 + fr][kk + fg8];
#pragma unroll
      for (int n = 0; n < 4; ++n) bfr[n] = *(const bf16x8*)&Bs[wn + n * 16 + fr][kk + fg8];
#pragma unroll
      for (int m = 0; m < 4; ++m)
#pragma unroll
        for (int n = 0; n < 4; ++n)
          acc[m][n] = __builtin_amdgcn_mfma_f32_16x16x32_bf16(af[m], bfr[n], acc[m][n], 0, 0, 0);
    }
  }
  // epilogue: C layout col=lane&15, row=(lane>>4)*4+reg
  const int cc = lane & 15, cg = (lane >> 4) * 4;
#pragma unroll
  for (int m = 0; m < 4; ++m) {
#pragma unroll
    for (int n = 0; n < 4; ++n) {
      const int col = n0 + wn + n * 16 + cc;
#pragma unroll
      for (int r = 0; r < 4; ++r) {
        const int row = m0 + wm + m * 16 + cg + r;
        const size_t idx = (size_t)row * N + col;
        if (MODE == 0) Cb[idx] = (bf16)acc[m][n][r];
        else           Xr[idx] += acc[m][n][r];
      }
    }
  }
}

// ======================= V transpose: VT[b][dh][n] = KV[b*NN+n][64+dh] ==========
__global__ void vt_kernel(const bf16* __restrict__ KV, bf16* __restrict__ VT) {
  __shared__ bf16 t[32][33];
  const int n0 = blockIdx.x * 32, d0 = blockIdx.y * 32, b = blockIdx.z;
  const int tx = threadIdx.x, ty = threadIdx.y;
#pragma unroll
  for (int k = 0; k < 4; ++k) {
    int n = n0 + ty + k * 8;
    t[ty + k * 8][tx] = KV[(size_t)(b * NN + n) * 128 + 64 + d0 + tx];
  }
  __syncthreads();
#pragma unroll
  for (int k = 0; k < 4; ++k) {
    int dh = d0 + ty + k * 8;
    VT[(size_t)(b * 64 + dh) * NN + n0 + tx] = t[tx][ty + k * 8];
  }
}

// ======================= attention ==========================
// 1 wave/block handles 16 q rows for one (b,h). Swapped QK^T: mfma(K,Q) -> lane
// holds S[q=lane&15][kv=(lane>>4)*4+r]. Online softmax in fp32. P via LDS to
// re-fragment for PV with VT (B operand contiguous loads).
__launch_bounds__(64)
__global__ void attn_kernel(const bf16* __restrict__ Q, const bf16* __restrict__ KV,
                            const bf16* __restrict__ VT, const float* __restrict__ btab,
                            bf16* __restrict__ O) {
  __shared__ bf16 P_lds[16][40];
  const int lane = threadIdx.x;
  const int qt = blockIdx.x, h = blockIdx.y, b = blockIdx.z;
  const int q0 = qt * 16;
  const int fr = lane & 15, fg = lane >> 4;
  const float* bt = btab + h * NN;
  bf16x8 qf0, qf1;
  {
    const size_t qoff = (size_t)(b * NN + q0 + fr) * INNER + h * DH + fg * 8;
    qf0 = *(const bf16x8*)(Q + qoff);
    qf1 = *(const bf16x8*)(Q + qoff + 32);
  }
  f32x4 Oacc[4] = {};
  float m_run = -1e30f, l_run = 0.0f;
  const int kv_end = q0 + 16;
  for (int kv0 = 0; kv0 < kv_end; kv0 += 32) {
    float sv[8];
    float mx = -1e30f;
#pragma unroll
    for (int t = 0; t < 2; ++t) {
      const size_t koff = (size_t)(b * NN + kv0 + t * 16 + fr) * 128 + fg * 8;
      bf16x8 kf0 = *(const bf16x8*)(KV + koff);
      bf16x8 kf1 = *(const bf16x8*)(KV + koff + 32);
      f32x4 z = {0.f, 0.f, 0.f, 0.f};
      z = __builtin_amdgcn_mfma_f32_16x16x32_bf16(kf0, qf0, z, 0, 0, 0);
      z = __builtin_amdgcn_mfma_f32_16x16x32_bf16(kf1, qf1, z, 0, 0, 0);
#pragma unroll
      for (int r = 0; r < 4; ++r) {
        const int kv = kv0 + t * 16 + fg * 4 + r;
        const int d = (q0 + fr) - kv;
        const int dc = d > 0 ? d : 0;
        float val = z[r] + bt[dc];
        if (d < 0) val = -1e30f;
        sv[t * 4 + r] = val;
        mx = fmaxf(mx, val);
      }
    }
    mx = fmaxf(mx, __shfl_xor(mx, 16));
    mx = fmaxf(mx, __shfl_xor(mx, 32));
    const float m_new = fmaxf(m_run, mx);
    const float sc_old = __expf(m_run - m_new);
    float csum = 0.0f;
#pragma unroll
    for (int i = 0; i < 8; ++i) { sv[i] = __expf(sv[i] - m_new); csum += sv[i]; }
    csum += __shfl_xor(csum, 16);
    csum += __shfl_xor(csum, 32);
    l_run = l_run * sc_old + csum;
    m_run = m_new;
    // rescale O (stats live per q=lane&15 in lanes 0..15; O rows are fg*4+r)
#pragma unroll
    for (int r = 0; r < 4; ++r) {
      const float f = __shfl(sc_old, fg * 4 + r);
#pragma unroll
      for (int c = 0; c < 4; ++c) Oacc[c][r] *= f;
    }
    // P -> LDS (bf16), re-read as A-fragment (row=q=lane&15, k=kv=fg*8..)
    bf16x4 p0, p1;
#pragma unroll
    for (int r = 0; r < 4; ++r) { p0[r] = (bf16)sv[r]; p1[r] = (bf16)sv[4 + r]; }
    *(bf16x4*)&P_lds[fr][fg * 4] = p0;
    *(bf16x4*)&P_lds[fr][16 + fg * 4] = p1;
    const bf16x8 pf = *(const bf16x8*)&P_lds[fr][fg * 8];
#pragma unroll
    for (int c = 0; c < 4; ++c) {
      const size_t voff = (size_t)(b * 64 + c * 16 + fr) * NN + kv0 + fg * 8;
      const bf16x8 vf = *(const bf16x8*)(VT + voff);
      Oacc[c] = __builtin_amdgcn_mfma_f32_16x16x32_bf16(pf, vf, Oacc[c], 0, 0, 0);
    }
  }
  const float linv = 1.0f / l_run;
#pragma unroll
  for (int r = 0; r < 4; ++r) {
    const float f = __shfl(linv, fg * 4 + r);
    const size_t orow = (size_t)(b * NN + q0 + fg * 4 + r) * INNER + h * DH;
#pragma unroll
    for (int c = 0; c < 4; ++c) O[orow + c * 16 + fr] = (bf16)(Oacc[c][r] * f);
  }
}

// ======================= GEGLU elementwise (in-place into hg) ===================
__global__ void gelu_mul_kernel(const bf16* __restrict__ ha, bf16* __restrict__ hg) {
  const size_t total = (size_t)MROW * FFP / 8;
  for (size_t i = (size_t)blockIdx.x * blockDim.x + threadIdx.x; i < total;
       i += (size_t)gridDim.x * blockDim.x) {
    bf16x8 a = *(const bf16x8*)(ha + i * 8);
    bf16x8 g = *(const bf16x8*)(hg + i * 8);
    bf16x8 r;
#pragma unroll
    for (int j = 0; j < 8; ++j) {
      float gv = (float)g[j], av = (float)a[j];
      float ge = 0.5f * gv * (1.0f + erff(gv * 0.70710678118654752f));
      r[j] = (bf16)(ge * av);
    }
    *(bf16x8*)(hg + i * 8) = r;
  }
}

// ======================= launch ==========================
extern "C" void kernel_launch(void* const* d_in, const int* in_sizes, int n_in,
                              void* d_out, int out_size, void* d_ws, size_t ws_size,
                              hipStream_t stream) {
  (void)in_sizes; (void)n_in; (void)out_size;
  const float* in_x  = (const float*)d_in[0];
  const float* rel   = (const float*)d_in[1];
  const float* ln1g  = (const float*)d_in[2];
  const float* ln1b  = (const float*)d_in[3];
  const float* wq    = (const float*)d_in[4];
  const float* wkv   = (const float*)d_in[5];
  const float* wo    = (const float*)d_in[6];
  const float* ln2g  = (const float*)d_in[7];
  const float* ln2b  = (const float*)d_in[8];
  const float* w1    = (const float*)d_in[9];
  const float* w2    = (const float*)d_in[10];
  const float* lnfg  = (const float*)d_in[11];
  const float* lnfb  = (const float*)d_in[12];
  float* out = (float*)d_out;

  // workspace layout (bf16 region then fp32 region) -- ~190 MiB total
  constexpr size_t E_WQ  = (size_t)INNER * DIM;      // 524288
  constexpr size_t E_WKV = (size_t)128 * DIM;        // 131072
  constexpr size_t E_WO  = (size_t)DIM * INNER;      // 524288
  constexpr size_t E_W1  = (size_t)FFP * DIM;        // 2883584
  constexpr size_t E_W2  = (size_t)DIM * FFP;        // 2883584
  bf16* wqT  = (bf16*)d_ws;
  bf16* wkvT = wqT  + NLAY * E_WQ;
  bf16* woT  = wkvT + NLAY * E_WKV;
  bf16* w1aT = woT  + NLAY * E_WO;
  bf16* w1gT = w1aT + NLAY * E_W1;
  bf16* w2T  = w1gT + NLAY * E_W1;
  bf16* xnb  = w2T  + NLAY * E_W2;
  bf16* qb   = xnb  + (size_t)MROW * DIM;
  bf16* kvb  = qb   + (size_t)MROW * INNER;
  bf16* vTb  = kvb  + (size_t)MROW * 128;
  bf16* ob   = vTb  + (size_t)NB * 64 * NN;
  bf16* hab  = ob   + (size_t)MROW * INNER;
  bf16* hgb  = hab  + (size_t)MROW * FFP;
  float* xbuf = (float*)(hgb + (size_t)MROW * FFP);
  float* btab = xbuf + (size_t)MROW * DIM;
  const size_t needed = (size_t)((char*)(btab + NH * NN) - (char*)d_ws);
  if (ws_size < needed) return;  // visible clean failure instead of corruption

  // x = grad_shrink(x) = x (forward identity)
  hipMemcpyAsync(xbuf, in_x, (size_t)MROW * DIM * sizeof(float),
                 hipMemcpyDeviceToDevice, stream);
  btab_kernel<<<8, 256, 0, stream>>>(rel, btab);

  const dim3 tb(32, 8);
  conv_tr<<<dim3(16, 32, 6), tb, 0, stream>>>(wq,  (size_t)DIM*INNER, INNER, 0, DIM, INNER,
                                              wqT,  E_WQ, DIM, 0.125f);   // fold DH^-0.5
  conv_tr<<<dim3(4, 32, 6),  tb, 0, stream>>>(wkv, (size_t)DIM*128, 128, 0, DIM, 128,
                                              wkvT, E_WKV, DIM, 1.0f);
  conv_tr<<<dim3(32, 16, 6), tb, 0, stream>>>(wo,  (size_t)INNER*DIM, DIM, 0, INNER, DIM,
                                              woT,  E_WO, INNER, 1.0f);
  conv_tr<<<dim3(88, 32, 6), tb, 0, stream>>>(w1,  (size_t)DIM*2*FF, 2*FF, 0, DIM, FF,
                                              w1aT, E_W1, DIM, 1.0f);
  conv_tr<<<dim3(88, 32, 6), tb, 0, stream>>>(w1,  (size_t)DIM*2*FF, 2*FF, FF, DIM, FF,
                                              w1gT, E_W1, DIM, 1.0f);
  conv_tr<<<dim3(32, 88, 6), tb, 0, stream>>>(w2,  (size_t)FF*DIM, DIM, 0, FF, DIM,
                                              w2T,  E_W2, FFP, 1.0f);

  for (int l = 0; l < NLAY; ++l) {
    ln_kernel<bf16><<<MROW, 256, 0, stream>>>(xbuf, ln1g + l*DIM, ln1b + l*DIM, xnb);
    gemm_bt<0><<<dim3(INNER/128, MROW/128), 256, 0, stream>>>(xnb, wqT + l*E_WQ, DIM, INNER, qb, nullptr);
    gemm_bt<0><<<dim3(1, MROW/128), 256, 0, stream>>>(xnb, wkvT + l*E_WKV, DIM, 128, kvb, nullptr);
    vt_kernel<<<dim3(NN/32, 2, NB), tb, 0, stream>>>(kvb, vTb);
    attn_kernel<<<dim3(NN/16, NH, NB), 64, 0, stream>>>(qb, kvb, vTb, btab, ob);
    gemm_bt<1><<<dim3(DIM/128, MROW/128), 256, 0, stream>>>(ob, woT + l*E_WO, INNER, DIM, nullptr, xbuf);
    ln_kernel<bf16><<<MROW, 256, 0, stream>>>(xbuf, ln2g + l*DIM, ln2b + l*DIM, xnb);
    gemm_bt<0><<<dim3(FFP/128, MROW/128), 256, 0, stream>>>(xnb, w1aT + l*E_W1, DIM, FFP, hab, nullptr);
    gemm_bt<0><<<dim3(FFP/128, MROW/128), 256, 0, stream>>>(xnb, w1gT + l*E_W1, DIM, FFP, hgb, nullptr);
    gelu_mul_kernel<<<2048, 256, 0, stream>>>(hab, hgb);
    gemm_bt<1><<<dim3(DIM/128, MROW/128), 256, 0, stream>>>(hgb, w2T + l*E_W2, FFP, DIM, nullptr, xbuf);
  }
  ln_kernel<float><<<MROW, 256, 0, stream>>>(xbuf, lnfg, lnfb, out);
}